// Round 7
// baseline (46.321 us; speedup 1.0000x reference)
//
#include <hip/hip_runtime.h>

typedef unsigned long long u64;

#define CC 32
#define NN 512
#define TT 12
#define NBLK 256     // one block per (batch, channel); == CU count
#define NTHR 256     // 2 n-elements per thread (proven shape)

// Per-batch slot region: 1024 u64 = 8KB apart (spread across HBM channels).
//   csum  (parity p, ch i): slots[b*1024 + p*32 + i]
//   xsum  (step t,  ch i):  slots[b*1024 + 64 + t*32 + i]
#define BATCH_STRIDE 1024
#define SLOT_TOTAL   (8*BATCH_STRIDE)

__device__ __forceinline__ float eluf(float x){ return x>0.f ? x : (__expf(x)-1.f); }
__device__ __forceinline__ float elu3f(float x){ return eluf(eluf(eluf(x))); }
__device__ __forceinline__ float sigmf(float x){
  if (x>=0.f) return 1.f/(1.f+__expf(-x));
  float e=__expf(x); return e/(1.f+e);
}
__device__ __forceinline__ float tanhff(float x){
  return 1.f - 2.f/(__expf(2.f*x)+1.f);   // exact at saturation
}
__device__ __forceinline__ u64 pack_slot(unsigned tag, float v){
  return ((u64)tag<<32) | (u64)__float_as_uint(v);
}
__device__ __forceinline__ u64 ld_slot(u64* p){
  return __hip_atomic_load(p, __ATOMIC_RELAXED, __HIP_MEMORY_SCOPE_AGENT);
}
__device__ __forceinline__ void st_slot(u64* p, u64 v){
  __hip_atomic_store(p, v, __ATOMIC_RELAXED, __HIP_MEMORY_SCOPE_AGENT);
}
__device__ __forceinline__ float poll_sleep(u64* p, unsigned want){
  u64 v = ld_slot(p);
  int guard = 0;
  while ((unsigned)(v>>32) != want){
    __builtin_amdgcn_s_sleep(1);
    v = ld_slot(p);
    if (++guard > 1000000) break;   // terminates instead of hanging
  }
  return __uint_as_float((unsigned)v);
}
__device__ __forceinline__ float poll_tight(u64* p, unsigned want){
  u64 v = ld_slot(p);
  int guard = 0;
  while ((unsigned)(v>>32) != want){
    v = ld_slot(p);
    if (++guard > 4000000) break;
  }
  return __uint_as_float((unsigned)v);
}

__global__ __launch_bounds__(NTHR, 1)
void glstm_fused(const float* __restrict__ xg,     // (B,C,N,T)
                 const float* __restrict__ cellg,  // (B,C,N)
                 const float* __restrict__ w1g,    // (T,8,C,C)
                 const float* __restrict__ w2g,    // (T,8,C,C)
                 const float* __restrict__ biasg,  // (4,C,N,T)
                 float* __restrict__ outg,         // (B,C,N,T) ++ (B,C,N)
                 u64* slots)
{
  // 96KB bias tile -> 1 block/CU (proven residency for the spin pipeline)
  __shared__ float biasL[4][TT][NN];
  __shared__ float csL[CC];          // this step's peer csums (wave-0 polled)
  __shared__ float preS[2][4];       // parity-buffered gate pre-activations
  __shared__ float redS[2][4];       // parity-buffered csum wave-partials
  __shared__ float wpart[13][4];

  const int blk  = blockIdx.x;
  const int b    = blk >> 5;         // r1/r6 mapping (XCD-local mapping hurts)
  const int ch   = blk & 31;
  const int tid  = threadIdx.x;
  const int lane = tid & 63;
  const int wv   = tid >> 6;         // 0..3
  const int i0   = lane & 31;

  u64* bslot = slots + b*BATCH_STRIDE;   // this batch's 8KB region
  // publish targets for this block's row (channel ch)
  u64* cs_pub = bslot + ch;              // + parity*32
  u64* xs_pub = bslot + 64 + ch;         // + t*32

  // ---- per-thread state: 2 n-elements ----
  const int n0 = 2*tid;
  float2 cc2 = *(const float2*)(cellg + blk*NN + n0);
  float c0 = cc2.x, c1 = cc2.y;

  // ---- bias -> LDS ----
  #pragma unroll
  for (int k=0;k<4;k++){
    #pragma unroll
    for (int half=0; half<2; half++){
      int n = tid + half*256;
      const float4* p = (const float4*)(biasg + ((k*CC + ch)*NN + n)*TT);
      float4 v0=p[0], v1=p[1], v2=p[2];
      biasL[k][0][n]=v0.x;  biasL[k][1][n]=v0.y;  biasL[k][2][n]=v0.z;  biasL[k][3][n]=v0.w;
      biasL[k][4][n]=v1.x;  biasL[k][5][n]=v1.y;  biasL[k][6][n]=v1.z;  biasL[k][7][n]=v1.w;
      biasL[k][8][n]=v2.x;  biasL[k][9][n]=v2.y;  biasL[k][10][n]=v2.z; biasL[k][11][n]=v2.w;
    }
  }

  // ---- x rowsums per t + csum(state0) ----
  float xs[TT];
  #pragma unroll
  for (int t=0;t<TT;t++) xs[t]=0.f;
  const float* xrow = xg + blk*NN*TT;
  #pragma unroll
  for (int half=0; half<2; half++){
    int n = tid + half*256;
    const float4* p = (const float4*)(xrow + n*TT);
    float4 v0=p[0], v1=p[1], v2=p[2];
    xs[0]+=v0.x;  xs[1]+=v0.y;  xs[2]+=v0.z;  xs[3]+=v0.w;
    xs[4]+=v1.x;  xs[5]+=v1.y;  xs[6]+=v1.z;  xs[7]+=v1.w;
    xs[8]+=v2.x;  xs[9]+=v2.y;  xs[10]+=v2.z; xs[11]+=v2.w;
  }
  float cp = c0 + c1;
  #pragma unroll
  for (int off=32; off>=1; off>>=1){
    #pragma unroll
    for (int t=0;t<TT;t++) xs[t] += __shfl_xor(xs[t], off, 64);
    cp += __shfl_xor(cp, off, 64);
  }
  if (lane == 0){
    #pragma unroll
    for (int t=0;t<TT;t++) wpart[t][wv] = xs[t];
    wpart[12][wv] = cp;
  }
  __syncthreads();
  if (tid < 13){
    float v = wpart[tid][0]+wpart[tid][1]+wpart[tid][2]+wpart[tid][3];
    if (tid < TT) st_slot(xs_pub + tid*32, pack_slot(1u, v));
    else          st_slot(cs_pub,          pack_slot(1u, v));  // parity 0
  }

  // ---- head assignment + weight double-buffer (t=0 now) ----
  const int m = wv + ((lane >> 5) << 2);   // lanes<32: x-heads 0-3; lanes>=32: c-heads 4-7
  float w1p[2][32];
  float w2p[2];
  {
    const float* w1m = w1g + m*CC*CC + i0;
    #pragma unroll
    for (int j=0;j<32;j++) w1p[0][j] = w1m[j*CC];
    w2p[0] = w2g[(m*CC + i0)*CC + ch];
  }

  // ---- gather ALL peer xsums to registers once (one-time; sleepy poll) ----
  float zxr[TT];
  #pragma unroll
  for (int t=0;t<TT;t++)
    zxr[t] = poll_sleep(bslot + 64 + t*32 + i0, 1u);

  // ---- 12 sequential steps, fully unrolled ----
  float hm0[TT], hm1[TT];
  #pragma unroll
  for (int s=0;s<TT;s++){
    // hop: ONLY wave 0 polls (32 wave-pollers per batch instead of 128)
    if (wv == 0){
      float pc = poll_tight(bslot + (s&1)*32 + i0, (unsigned)(s+1));
      if (lane < 32) csL[i0] = pc;
    }
    __syncthreads();   // B0: csL ready

    // heads: lanes<32 x-head (regs), lanes>=32 c-head (csL broadcast read)
    float zs = (lane < 32) ? zxr[s] : csL[i0];
    float pa = 0.f, pb = 0.f;
    #pragma unroll
    for (int j=0;j<16;j++){
      pa = fmaf(__shfl(zs, j,    32), w1p[s&1][j],    pa);
      pb = fmaf(__shfl(zs, j+16, 32), w1p[s&1][j+16], pb);
    }
    float s1 = pa + pb;
    float h1 = eluf(eluf(s1));
    float pp = h1 * w2p[s&1];
    #pragma unroll
    for (int off=16; off>=1; off>>=1) pp += __shfl_xor(pp, off, 32);
    float ov = elu3f(512.f*pp);
    float prew = ov + __shfl_xor(ov, 32, 64);      // x-head + c-head
    if (lane == 0) preS[s&1][wv] = prew;

    // bias -> regs before the barrier (gate phase = pure VALU)
    float b00 = biasL[0][s][n0], b01 = biasL[0][s][n0+1];
    float b10 = biasL[1][s][n0], b11 = biasL[1][s][n0+1];
    float b20 = biasL[2][s][n0], b21 = biasL[2][s][n0+1];
    float b30 = biasL[3][s][n0], b31 = biasL[3][s][n0+1];

    __syncthreads();   // B1: preS[s&1] ready
    const float g0 = preS[s&1][0], g1 = preS[s&1][1];
    const float g2 = preS[s&1][2], g3 = preS[s&1][3];

    float ig0 = sigmf(g0 + b00);
    float fg0 = sigmf(g1 + b10);
    float ct0 = tanhff(g3 + b30);
    float ig1 = sigmf(g0 + b01);
    float fg1 = sigmf(g1 + b11);
    float ct1 = tanhff(g3 + b31);
    c0 = fg0*c0 + ig0*ct0;
    c1 = fg1*c1 + ig1*ct1;

    if (s < TT-1){
      const int par = (s+1)&1;
      float csp = c0 + c1;
      #pragma unroll
      for (int off=32; off>=1; off>>=1) csp += __shfl_xor(csp, off, 64);
      if (lane == 0) redS[par][wv] = csp;
      __syncthreads(); // B2: redS ready
      if (tid == 0){
        float tot = redS[par][0]+redS[par][1]+redS[par][2]+redS[par][3];
        st_slot(cs_pub + par*32, pack_slot((unsigned)(s+2), tot));
      }
      // prefetch next step's weights AFTER the publish point
      const float* w1m = w1g + ((s+1)*8 + m)*CC*CC + i0;
      #pragma unroll
      for (int j=0;j<32;j++) w1p[par][j] = w1m[j*CC];
      w2p[par] = w2g[(((s+1)*8 + m)*CC + i0)*CC + ch];
    }

    hm0[s] = sigmf(g2 + b20) * tanhff(c0);
    hm1[s] = sigmf(g2 + b21) * tanhff(c1);
  }

  // ---- coalesced epilogue ----
  float4* op = (float4*)(outg + (blk*NN + n0)*TT);
  op[0] = make_float4(hm0[0], hm0[1], hm0[2],  hm0[3]);
  op[1] = make_float4(hm0[4], hm0[5], hm0[6],  hm0[7]);
  op[2] = make_float4(hm0[8], hm0[9], hm0[10], hm0[11]);
  op[3] = make_float4(hm1[0], hm1[1], hm1[2],  hm1[3]);
  op[4] = make_float4(hm1[4], hm1[5], hm1[6],  hm1[7]);
  op[5] = make_float4(hm1[8], hm1[9], hm1[10], hm1[11]);
  *(float2*)(outg + NBLK*NN*TT + blk*NN + n0) = make_float2(c0, c1);
}

extern "C" void kernel_launch(void* const* d_in, const int* in_sizes, int n_in,
                              void* d_out, int out_size, void* d_ws, size_t ws_size,
                              hipStream_t stream)
{
  (void)in_sizes; (void)n_in; (void)out_size; (void)ws_size;
  // setup_inputs order: input, cell, adj, w1, a1, w2, a2, bias
  const float* xg    = (const float*)d_in[0];
  const float* cellg = (const float*)d_in[1];
  const float* w1g   = (const float*)d_in[3];
  const float* w2g   = (const float*)d_in[5];
  const float* biasg = (const float*)d_in[7];
  float* outg = (float*)d_out;
  u64* slots = (u64*)d_ws;

  // reset sync tags every launch (ws is not re-poisoned between replays)
  hipMemsetAsync(d_ws, 0, (size_t)SLOT_TOTAL*sizeof(u64), stream);
  glstm_fused<<<dim3(NBLK), dim3(NTHR), 0, stream>>>(xg, cellg, w1g, w2g, biasg, outg, slots);
}

// Round 8
// 43.534 us; speedup vs baseline: 1.0640x; 1.0640x over previous
//
#include <hip/hip_runtime.h>

typedef unsigned long long u64;

#define CC 32
#define NN 512
#define TT 12
#define NBLK 256     // one block per (batch, channel); == CU count
#define NTHR 256     // 2 n-elements per thread (proven shape)

__device__ __forceinline__ float eluf(float x){ return x>0.f ? x : (__expf(x)-1.f); }
__device__ __forceinline__ float elu3f(float x){ return eluf(eluf(eluf(x))); }
__device__ __forceinline__ float sigmf(float x){
  if (x>=0.f) return 1.f/(1.f+__expf(-x));
  float e=__expf(x); return e/(1.f+e);
}
__device__ __forceinline__ float tanhff(float x){
  return 1.f - 2.f/(__expf(2.f*x)+1.f);   // exact at saturation
}
__device__ __forceinline__ u64 pack_slot(unsigned tag, float v){
  return ((u64)tag<<32) | (u64)__float_as_uint(v);
}
__device__ __forceinline__ u64 ld_slot(u64* p){
  return __hip_atomic_load(p, __ATOMIC_RELAXED, __HIP_MEMORY_SCOPE_AGENT);
}
// Publish via atomic RMW: executes at the memory-side atomic unit -> visible
// on acceptance, no partial-line write-through/drain-buffer delay (the prime
// suspect for the ~3 us/step hop cost; plain relaxed store is the r6 baseline).
__device__ __forceinline__ void xch_slot(u64* p, u64 v){
  (void)__hip_atomic_exchange(p, v, __ATOMIC_RELAXED, __HIP_MEMORY_SCOPE_AGENT);
}
__device__ __forceinline__ float poll_slot(u64* p, unsigned want){
  u64 v = ld_slot(p);
  int guard = 0;
  while ((unsigned)(v>>32) != want){
    __builtin_amdgcn_s_sleep(1);
    v = ld_slot(p);
    if (++guard > 1000000) break;   // terminates instead of hanging
  }
  return __uint_as_float((unsigned)v);
}

__global__ __launch_bounds__(NTHR, 1)
void glstm_fused(const float* __restrict__ xg,     // (B,C,N,T)
                 const float* __restrict__ cellg,  // (B,C,N)
                 const float* __restrict__ w1g,    // (T,8,C,C)
                 const float* __restrict__ w2g,    // (T,8,C,C)
                 const float* __restrict__ biasg,  // (4,C,N,T)
                 float* __restrict__ outg,         // (B,C,N,T) ++ (B,C,N)
                 u64* slots)
{
  // 96KB bias tile -> 1 block/CU (proven residency for the spin pipeline)
  __shared__ float biasL[4][TT][NN];
  __shared__ float preS[2][4];       // parity-buffered gate pre-activations
  __shared__ float redS[2][4];       // parity-buffered csum wave-partials
  __shared__ float wpart[13][4];

  const int blk  = blockIdx.x;
  const int b    = blk >> 5;         // proven mapping (XCD-local mapping hurts)
  const int ch   = blk & 31;
  const int row  = blk;
  const int tid  = threadIdx.x;
  const int lane = tid & 63;
  const int wv   = tid >> 6;         // 0..3
  const int i0   = lane & 31;

  u64* cs_slot = slots;              // [2][NBLK] tagged csum, parity-buffered
  u64* xs_slot = slots + 2*NBLK;     // [TT][NBLK] tagged xsum, tag=1

  // ---- per-thread state: 2 n-elements ----
  const int n0 = 2*tid;
  float2 cc2 = *(const float2*)(cellg + row*NN + n0);
  float c0 = cc2.x, c1 = cc2.y;

  // ---- x rowsums per t + csum(state0) FIRST (publish before bias staging:
  //      the whole batch group is gated on the last publisher) ----
  float xs[TT];
  #pragma unroll
  for (int t=0;t<TT;t++) xs[t]=0.f;
  const float* xrow = xg + row*NN*TT;
  #pragma unroll
  for (int half=0; half<2; half++){
    int n = tid + half*256;
    const float4* p = (const float4*)(xrow + n*TT);
    float4 v0=p[0], v1=p[1], v2=p[2];
    xs[0]+=v0.x;  xs[1]+=v0.y;  xs[2]+=v0.z;  xs[3]+=v0.w;
    xs[4]+=v1.x;  xs[5]+=v1.y;  xs[6]+=v1.z;  xs[7]+=v1.w;
    xs[8]+=v2.x;  xs[9]+=v2.y;  xs[10]+=v2.z; xs[11]+=v2.w;
  }
  float cp = c0 + c1;
  #pragma unroll
  for (int off=32; off>=1; off>>=1){
    #pragma unroll
    for (int t=0;t<TT;t++) xs[t] += __shfl_xor(xs[t], off, 64);
    cp += __shfl_xor(cp, off, 64);
  }
  if (lane == 0){
    #pragma unroll
    for (int t=0;t<TT;t++) wpart[t][wv] = xs[t];
    wpart[12][wv] = cp;
  }
  __syncthreads();
  if (tid < 13){
    float v = wpart[tid][0]+wpart[tid][1]+wpart[tid][2]+wpart[tid][3];
    if (tid < TT) xch_slot(&xs_slot[tid*NBLK + row], pack_slot(1u, v));
    else          xch_slot(&cs_slot[row],            pack_slot(1u, v));  // parity 0
  }

  // ---- bias -> LDS (after publish; overlaps peers' publish latency) ----
  #pragma unroll
  for (int k=0;k<4;k++){
    #pragma unroll
    for (int half=0; half<2; half++){
      int n = tid + half*256;
      const float4* p = (const float4*)(biasg + ((k*CC + ch)*NN + n)*TT);
      float4 v0=p[0], v1=p[1], v2=p[2];
      biasL[k][0][n]=v0.x;  biasL[k][1][n]=v0.y;  biasL[k][2][n]=v0.z;  biasL[k][3][n]=v0.w;
      biasL[k][4][n]=v1.x;  biasL[k][5][n]=v1.y;  biasL[k][6][n]=v1.z;  biasL[k][7][n]=v1.w;
      biasL[k][8][n]=v2.x;  biasL[k][9][n]=v2.y;  biasL[k][10][n]=v2.z; biasL[k][11][n]=v2.w;
    }
  }

  // ---- head assignment + weight double-buffer (t=0 now) ----
  const int m = wv + ((lane >> 5) << 2);   // lanes<32: x-heads 0-3; lanes>=32: c-heads 4-7
  float w1p[2][32];
  float w2p[2];
  {
    const float* w1m = w1g + m*CC*CC + i0;
    #pragma unroll
    for (int j=0;j<32;j++) w1p[0][j] = w1m[j*CC];
    w2p[0] = w2g[(m*CC + i0)*CC + ch];
  }

  // ---- gather ALL peer xsums to registers once ----
  float zxr[TT];
  #pragma unroll
  for (int t=0;t<TT;t++)
    zxr[t] = poll_slot(&xs_slot[t*NBLK + b*CC + i0], 1u);

  // ---- 12 sequential steps, fully unrolled, 2 barriers/step ----
  float hm0[TT], hm1[TT];
  #pragma unroll
  for (int s=0;s<TT;s++){
    // hop: all lanes poll this step's peer csum
    float csv = poll_slot(&cs_slot[(s&1)*NBLK + b*CC + i0], (unsigned)(s+1));
    float zs = (lane < 32) ? zxr[s] : csv;

    // head matvec from prefetched registers (no global loads post-poll)
    float pa = 0.f, pb = 0.f;
    #pragma unroll
    for (int j=0;j<16;j++){
      pa = fmaf(__shfl(zs, j,    32), w1p[s&1][j],    pa);
      pb = fmaf(__shfl(zs, j+16, 32), w1p[s&1][j+16], pb);
    }
    float s1 = pa + pb;
    float h1 = eluf(eluf(s1));
    float pp = h1 * w2p[s&1];
    #pragma unroll
    for (int off=16; off>=1; off>>=1) pp += __shfl_xor(pp, off, 32);
    float ov = elu3f(512.f*pp);
    float prew = ov + __shfl_xor(ov, 32, 64);      // x-head + c-head
    if (lane == 0) preS[s&1][wv] = prew;

    // bias -> regs before the barrier (gate phase = pure VALU)
    float b00 = biasL[0][s][n0], b01 = biasL[0][s][n0+1];
    float b10 = biasL[1][s][n0], b11 = biasL[1][s][n0+1];
    float b20 = biasL[2][s][n0], b21 = biasL[2][s][n0+1];
    float b30 = biasL[3][s][n0], b31 = biasL[3][s][n0+1];

    __syncthreads();   // B1: preS[s&1] ready
    const float g0 = preS[s&1][0], g1 = preS[s&1][1];
    const float g2 = preS[s&1][2], g3 = preS[s&1][3];

    float ig0 = sigmf(g0 + b00);
    float fg0 = sigmf(g1 + b10);
    float ct0 = tanhff(g3 + b30);
    float ig1 = sigmf(g0 + b01);
    float fg1 = sigmf(g1 + b11);
    float ct1 = tanhff(g3 + b31);
    c0 = fg0*c0 + ig0*ct0;
    c1 = fg1*c1 + ig1*ct1;

    if (s < TT-1){
      const int par = (s+1)&1;
      float csp = c0 + c1;
      #pragma unroll
      for (int off=32; off>=1; off>>=1) csp += __shfl_xor(csp, off, 64);
      if (lane == 0) redS[par][wv] = csp;
      __syncthreads(); // B2: redS ready (also fences preS for next parity reuse)
      if (tid == 0){
        float tot = redS[par][0]+redS[par][1]+redS[par][2]+redS[par][3];
        xch_slot(&cs_slot[par*NBLK + row], pack_slot((unsigned)(s+2), tot));
      }
      // prefetch next step's weights AFTER the publish point
      const float* w1m = w1g + ((s+1)*8 + m)*CC*CC + i0;
      #pragma unroll
      for (int j=0;j<32;j++) w1p[par][j] = w1m[j*CC];
      w2p[par] = w2g[(((s+1)*8 + m)*CC + i0)*CC + ch];
    }

    hm0[s] = sigmf(g2 + b20) * tanhff(c0);
    hm1[s] = sigmf(g2 + b21) * tanhff(c1);
  }

  // ---- coalesced epilogue: 2 n-rows x 12 t contiguous ----
  float4* op = (float4*)(outg + (row*NN + n0)*TT);
  op[0] = make_float4(hm0[0], hm0[1], hm0[2],  hm0[3]);
  op[1] = make_float4(hm0[4], hm0[5], hm0[6],  hm0[7]);
  op[2] = make_float4(hm0[8], hm0[9], hm0[10], hm0[11]);
  op[3] = make_float4(hm1[0], hm1[1], hm1[2],  hm1[3]);
  op[4] = make_float4(hm1[4], hm1[5], hm1[6],  hm1[7]);
  op[5] = make_float4(hm1[8], hm1[9], hm1[10], hm1[11]);
  *(float2*)(outg + NBLK*NN*TT + row*NN + n0) = make_float2(c0, c1);
}

extern "C" void kernel_launch(void* const* d_in, const int* in_sizes, int n_in,
                              void* d_out, int out_size, void* d_ws, size_t ws_size,
                              hipStream_t stream)
{
  (void)in_sizes; (void)n_in; (void)out_size; (void)ws_size;
  // setup_inputs order: input, cell, adj, w1, a1, w2, a2, bias
  const float* xg    = (const float*)d_in[0];
  const float* cellg = (const float*)d_in[1];
  const float* w1g   = (const float*)d_in[3];
  const float* w2g   = (const float*)d_in[5];
  const float* biasg = (const float*)d_in[7];
  float* outg = (float*)d_out;
  u64* slots = (u64*)d_ws;

  // reset sync tags every launch (ws is not re-poisoned between replays)
  hipMemsetAsync(d_ws, 0, (size_t)(2*NBLK + TT*NBLK)*sizeof(u64), stream);
  glstm_fused<<<dim3(NBLK), dim3(NTHR), 0, stream>>>(xg, cellg, w1g, w2g, biasg, outg, slots);
}